// Round 6
// baseline (94.820 us; speedup 1.0000x reference)
//
#include <hip/hip_runtime.h>
#include <stdint.h>

// ExpertLoRA: N=8192, Z=1024, H=2048, W=64, R=8, SCALE=1.0
// Round 5: max TLP. One token per wave (TW=1), TB=8, 512-thr blocks,
// 1088 blocks (~4/CU). LDS only for phase-2 b1/a2 chunk double-buffer
// (32 KB); a1/b2 streamed directly from global (L1/L2-served).

constexpr int Zd = 1024;
constexpr int Hd = 2048;
constexpr int Rr = 8;
constexpr int Wn = 64;
constexpr int TB = 8;            // tokens per block = waves per block
constexpr int NT = 512;          // threads per block
constexpr int HC = 256;          // phase-2 H chunk (elements)
constexpr int NCHUNK = Hd / HC;  // 8
constexpr float kScale = 1.0f;

// ws layout (ints): [0]=n_blocks, [16..16+N)=order, then int4 block table.

__global__ __launch_bounds__(1024) void bucket_kernel(
    const int* __restrict__ a_idx, int N, int* __restrict__ ws)
{
    __shared__ int hist[Wn];
    __shared__ int cursor[Wn];
    const int t = threadIdx.x;
    if (t < Wn) hist[t] = 0;
    __syncthreads();
    for (int i = t; i < N; i += 1024) atomicAdd(&hist[a_idx[i]], 1);
    __syncthreads();

    if (t < Wn) {                       // wave 0 does both prefix scans
        const int c = hist[t];
        int scan = c;
#pragma unroll
        for (int off = 1; off < 64; off <<= 1) {
            const int v = __shfl_up(scan, off, 64);
            if (t >= off) scan += v;
        }
        const int base = scan - c;

        const int nb_e = (c + TB - 1) / TB;
        int bs = nb_e;
#pragma unroll
        for (int off = 1; off < 64; off <<= 1) {
            const int v = __shfl_up(bs, off, 64);
            if (t >= off) bs += v;
        }
        const int bstart = bs - nb_e;
        if (t == Wn - 1) ws[0] = bs;
        cursor[t] = base;

        int4* btab = (int4*)(ws + 16 + N);
        for (int s = 0, k = 0; s < c; s += TB, ++k)
            btab[bstart + k] = make_int4(t, base + s, min(TB, c - s), 0);
    }
    __syncthreads();
    int* order = ws + 16;
    for (int i = t; i < N; i += 1024) {
        const int pos = atomicAdd(&cursor[a_idx[i]], 1);
        order[pos] = i;
    }
}

__device__ __forceinline__ float wave_allreduce(float v) {
#pragma unroll
    for (int off = 1; off < 64; off <<= 1)
        v += __shfl_xor(v, off, 64);
    return v;
}

__device__ __forceinline__ float dot8(const float* t, float4 w0, float4 w1) {
    return fmaf(t[0], w0.x, fmaf(t[1], w0.y, fmaf(t[2], w0.z, fmaf(t[3], w0.w,
           fmaf(t[4], w1.x, fmaf(t[5], w1.y, fmaf(t[6], w1.z, t[7] * w1.w)))))));
}

__device__ __forceinline__ float silu(float x) {
    return x * __builtin_amdgcn_rcpf(1.f + __expf(-x));
}

// XOR swizzle: involution on byte offsets (bits 4-6 ^= bits 7-9).
__device__ __forceinline__ int swz(int o) {
    return o ^ (((o >> 7) & 7) << 4);
}

// async global -> LDS, 16 B per lane. LDS dest is wave-uniform base
// (HW adds lane*16); global src is per-lane.
__device__ __forceinline__ void stage16(const void* g, void* l) {
    __builtin_amdgcn_global_load_lds(
        (const __attribute__((address_space(1))) uint32_t*)g,
        (__attribute__((address_space(3))) uint32_t*)l, 16, 0, 0);
}

__global__ __launch_bounds__(NT, 8) void lora_main(
    const float* __restrict__ z,        // [N, Z]
    const float* __restrict__ h_pre,    // [N, H]
    const float* __restrict__ out_pre,  // [N, Z]
    const float* __restrict__ a1,       // [W, R, Z]
    const float* __restrict__ b1,       // [W, H, R]
    const float* __restrict__ a2,       // [W, R, H]
    const float* __restrict__ b2,       // [W, Z, R]
    float* __restrict__ out,            // [N, Z]
    const int* __restrict__ ws, int N)
{
    __shared__ float s_b1[2][HC * Rr];   // 2 x 8 KB
    __shared__ float s_a2[2][Rr * HC];   // 2 x 8 KB

    const int cpx = gridDim.x >> 3;
    const int lb  = (blockIdx.x & 7) * cpx + (blockIdx.x >> 3);
    if (lb >= ws[0]) return;

    const int4 desc = ((const int4*)(ws + 16 + N))[lb];
    const int e = desc.x, start = desc.y, cnt = desc.z;
    const int* order = ws + 16;

    const int t    = threadIdx.x;
    const int wave = t >> 6;
    const int lane = t & 63;

    const bool val = (wave < cnt);
    const int  tok = order[start + (val ? wave : 0)];

    const float4* A1  = (const float4*)(a1 + (size_t)e * (Rr * Zd));
    const char*   b1e = (const char*)(b1 + (size_t)e * (Hd * Rr));
    const float*  a2e = a2 + (size_t)e * (Rr * Hd);
    const float4* B2  = (const float4*)(b2 + (size_t)e * (Zd * Rr));

    // ---- stage phase-2 chunk 0 early (latency hidden under phase 1) ----
    {
        const int o = t * 16;                       // 8 KB b1 chunk, swizzled
        stage16(b1e + swz(o), (char*)s_b1[0] + wave * 1024);
        stage16(a2e + wave * Hd + lane * 4,         // wave w = row r=w, 1 KB
                (char*)s_a2[0] + wave * 1024);
    }

    // ---------- Phase 1: t1[r] = sum_d z[tok,d] * a1[e,r,d] (global a1) ----
    const float4* Zp = (const float4*)(z + (size_t)tok * Zd);

    float p[Rr];
#pragma unroll
    for (int r = 0; r < Rr; ++r) p[r] = 0.f;

#pragma unroll
    for (int i = 0; i < Zd / 4 / 64; ++i) {         // 4 iters
        const int c = lane + i * 64;
        const float4 zv = Zp[c];
#pragma unroll
        for (int r = 0; r < Rr; ++r) {
            const float4 w = A1[r * (Zd / 4) + c];
            p[r] = fmaf(zv.x, w.x, fmaf(zv.y, w.y,
                   fmaf(zv.z, w.z, fmaf(zv.w, w.w, p[r]))));
        }
    }
    float t1[Rr];
#pragma unroll
    for (int r = 0; r < Rr; ++r) t1[r] = wave_allreduce(p[r]);

    __syncthreads();   // chunk-0 staging drained (vmcnt(0) at barrier)

    // ---------- Phase 2: chunked over H, double-buffered ----------
    const float4* Hp = (const float4*)(h_pre + (size_t)tok * Hd);

    float q[Rr];
#pragma unroll
    for (int r = 0; r < Rr; ++r) q[r] = 0.f;

    for (int kc = 0; kc < NCHUNK; ++kc) {
        const int cur = kc & 1;
        if (kc + 1 < NCHUNK) {          // issue next chunk BEFORE compute
            const int nxt = cur ^ 1;
            const int hb = (kc + 1) * HC;
            const int o = t * 16;
            stage16(b1e + (size_t)hb * Rr * 4 + swz(o),
                    (char*)s_b1[nxt] + wave * 1024);
            stage16(a2e + wave * Hd + hb + lane * 4,
                    (char*)s_a2[nxt] + wave * 1024);
        }

        const int cc = kc * 64 + lane;              // float4 idx into H row
        const float4 hv = Hp[cc];

        float sv[4];
#pragma unroll
        for (int j = 0; j < 4; ++j) {
            const int o0 = lane * 128 + j * 32;     // row (4*lane+j) of chunk
            const float4 w0 = *(const float4*)((const char*)s_b1[cur] + swz(o0));
            const float4 w1 = *(const float4*)((const char*)s_b1[cur] + swz(o0 + 16));
            const float x = (&hv.x)[j] + dot8(t1, w0, w1) * kScale;
            sv[j] = silu(x);
        }
#pragma unroll
        for (int r = 0; r < Rr; ++r) {
            const float4 aw = *(const float4*)(s_a2[cur] + r * HC + lane * 4);
            q[r] = fmaf(sv[0], aw.x, fmaf(sv[1], aw.y,
                   fmaf(sv[2], aw.z, fmaf(sv[3], aw.w, q[r]))));
        }
        __syncthreads();   // all waves done with cur; next staging drained
    }

    float t2[Rr];
#pragma unroll
    for (int r = 0; r < Rr; ++r) t2[r] = wave_allreduce(q[r]) * kScale;

    // ---------- Phase 3: out = out_pre + t2·b2[e,d,:] (global b2) ----------
    const float4* Op = (const float4*)(out_pre + (size_t)tok * Zd);
    float4*       Xp = (float4*)(out + (size_t)tok * Zd);

#pragma unroll
    for (int i = 0; i < Zd / 4 / 64; ++i) {         // 4 iters
        const int c = lane + i * 64;
        const float4 ov = Op[c];
        float4 res;
#pragma unroll
        for (int j = 0; j < 4; ++j) {
            const float4 w0 = B2[(4 * c + j) * 2 + 0];
            const float4 w1 = B2[(4 * c + j) * 2 + 1];
            (&res.x)[j] = (&ov.x)[j] + dot8(t2, w0, w1);
        }
        if (val) Xp[c] = res;
    }
}

extern "C" void kernel_launch(void* const* d_in, const int* in_sizes, int n_in,
                              void* d_out, int out_size, void* d_ws, size_t ws_size,
                              hipStream_t stream) {
    const float* z       = (const float*)d_in[0];
    const int*   a_idx   = (const int*)d_in[1];
    const float* h_pre   = (const float*)d_in[2];
    const float* out_pre = (const float*)d_in[3];
    const float* a1      = (const float*)d_in[4];
    const float* b1      = (const float*)d_in[5];
    const float* a2      = (const float*)d_in[6];
    const float* b2      = (const float*)d_in[7];
    float* out = (float*)d_out;

    const int N = in_sizes[1];  // a_idx count

    bucket_kernel<<<1, 1024, 0, stream>>>(a_idx, N, (int*)d_ws);

    int nwg = N / TB + Wn;              // 1088 blocks (incl. per-expert tails)
    nwg = (nwg + 7) & ~7;               // multiple of 8 for XCD swizzle
    lora_main<<<nwg, NT, 0, stream>>>(z, h_pre, out_pre, a1, b1, a2, b2, out,
                                      (const int*)d_ws, N);
}

// Round 7
// 57.830 us; speedup vs baseline: 1.6396x; 1.6396x over previous
//
#include <hip/hip_runtime.h>
#include <stdint.h>

// ExpertLoRA: N=8192, Z=1024, H=2048, W=64, R=8, SCALE=1.0
// Round 6: R5 structure (LDS-staged weights, TW-token amortization) +
// T3/T4 counted-vmcnt pipeline: raw s_barrier (no vmcnt(0) drain),
// 3-deep phase-2 chunk buffers, stage issue AFTER barrier (race-free).
// NT=512 (8 waves), TW=2, TB=16 -> 576 blocks, 80 KB LDS -> 2 blocks/CU.

constexpr int Zd = 1024;
constexpr int Hd = 2048;
constexpr int Rr = 8;
constexpr int Wn = 64;
constexpr int TB = 16;           // tokens per block
constexpr int TW = 2;            // tokens per wave
constexpr int NT = 512;          // threads per block
constexpr int HC = 256;          // phase-2 H chunk (elements)
constexpr int NCHUNK = Hd / HC;  // 8
constexpr float kScale = 1.0f;

// ws layout (ints): [0]=n_blocks, [16..16+N)=order, then int4 block table.

__global__ __launch_bounds__(1024) void bucket_kernel(
    const int* __restrict__ a_idx, int N, int* __restrict__ ws)
{
    __shared__ int hist[Wn];
    __shared__ int cursor[Wn];
    const int t = threadIdx.x;
    if (t < Wn) hist[t] = 0;
    __syncthreads();
    for (int i = t; i < N; i += 1024) atomicAdd(&hist[a_idx[i]], 1);
    __syncthreads();

    if (t < Wn) {                       // wave 0 does both prefix scans
        const int c = hist[t];
        int scan = c;
#pragma unroll
        for (int off = 1; off < 64; off <<= 1) {
            const int v = __shfl_up(scan, off, 64);
            if (t >= off) scan += v;
        }
        const int base = scan - c;

        const int nb_e = (c + TB - 1) / TB;
        int bs = nb_e;
#pragma unroll
        for (int off = 1; off < 64; off <<= 1) {
            const int v = __shfl_up(bs, off, 64);
            if (t >= off) bs += v;
        }
        const int bstart = bs - nb_e;
        if (t == Wn - 1) ws[0] = bs;
        cursor[t] = base;

        int4* btab = (int4*)(ws + 16 + N);
        for (int s = 0, k = 0; s < c; s += TB, ++k)
            btab[bstart + k] = make_int4(t, base + s, min(TB, c - s), 0);
    }
    __syncthreads();
    int* order = ws + 16;
    for (int i = t; i < N; i += 1024) {
        const int pos = atomicAdd(&cursor[a_idx[i]], 1);
        order[pos] = i;
    }
}

__device__ __forceinline__ float wave_allreduce(float v) {
#pragma unroll
    for (int off = 1; off < 64; off <<= 1)
        v += __shfl_xor(v, off, 64);
    return v;
}

__device__ __forceinline__ float dot8(const float* t, float4 w0, float4 w1) {
    return fmaf(t[0], w0.x, fmaf(t[1], w0.y, fmaf(t[2], w0.z, fmaf(t[3], w0.w,
           fmaf(t[4], w1.x, fmaf(t[5], w1.y, fmaf(t[6], w1.z, t[7] * w1.w)))))));
}

__device__ __forceinline__ float silu(float x) {
    return x * __builtin_amdgcn_rcpf(1.f + __expf(-x));
}

// XOR swizzle: involution on byte offsets (bits 4-6 ^= bits 7-9).
__device__ __forceinline__ int swz(int o) {
    return o ^ (((o >> 7) & 7) << 4);
}

// async global -> LDS, 16 B per lane. LDS dest is wave-uniform base
// (HW adds lane*16); global src is per-lane.
__device__ __forceinline__ void stage16(const void* g, void* l) {
    __builtin_amdgcn_global_load_lds(
        (const __attribute__((address_space(1))) uint32_t*)g,
        (__attribute__((address_space(3))) uint32_t*)l, 16, 0, 0);
}

// Counted waits + raw barrier (no compiler vmcnt(0) drain).
#define WAITVM(N) asm volatile("s_waitcnt vmcnt(" #N ")" ::: "memory")
#define SYNC()    asm volatile("s_waitcnt lgkmcnt(0)\ns_barrier" ::: "memory")

__global__ __launch_bounds__(NT, 4) void lora_main(
    const float* __restrict__ z,        // [N, Z]
    const float* __restrict__ h_pre,    // [N, H]
    const float* __restrict__ out_pre,  // [N, Z]
    const float* __restrict__ a1,       // [W, R, Z]
    const float* __restrict__ b1,       // [W, H, R]
    const float* __restrict__ a2,       // [W, R, H]
    const float* __restrict__ b2,       // [W, Z, R]
    float* __restrict__ out,            // [N, Z]
    const int* __restrict__ ws, int N)
{
    __shared__ float s_a1[Rr * Zd];      // 32 KB: a1, then b2 for phase 3
    __shared__ float s_b1[3][HC * Rr];   // 3 x 8 KB
    __shared__ float s_a2[3][Rr * HC];   // 3 x 8 KB

    const int cpx = gridDim.x >> 3;
    const int lb  = (blockIdx.x & 7) * cpx + (blockIdx.x >> 3);
    if (lb >= ws[0]) return;

    const int4 desc = ((const int4*)(ws + 16 + N))[lb];
    const int e = desc.x, start = desc.y, cnt = desc.z;
    const int* order = ws + 16;

    const int t    = threadIdx.x;
    const int wave = t >> 6;
    const int lane = t & 63;

    bool val[TW];
    int  tok[TW];
#pragma unroll
    for (int k = 0; k < TW; ++k) {
        const int idx = wave * TW + k;
        val[k] = (idx < cnt);
        tok[k] = order[start + (val[k] ? idx : 0)];
    }

    const char*  a1e = (const char*)(a1 + (size_t)e * (Rr * Zd));
    const char*  b1e = (const char*)(b1 + (size_t)e * (Hd * Rr));
    const float* a2e = a2 + (size_t)e * (Rr * Hd);
    const char*  b2e = (const char*)(b2 + (size_t)e * (Zd * Rr));

    // ---- prologue staging: a1 (4 ops), chunk0 (2 ops), chunk1 (2 ops) ----
#pragma unroll
    for (int i = 0; i < 4; ++i) {
        const int o = (i * NT + t) * 16;
        stage16(a1e + o, (char*)s_a1 + (i * NT + wave * 64) * 16);
    }
#pragma unroll
    for (int c0 = 0; c0 < 2; ++c0) {
        const int o = t * 16;
        stage16(b1e + (size_t)(c0 * HC) * Rr * 4 + swz(o),
                (char*)s_b1[c0] + wave * 1024);
        stage16(a2e + wave * Hd + c0 * HC + lane * 4,
                (char*)s_a2[c0] + wave * 1024);
    }
    WAITVM(4);     // a1 landed; chunk0/1 (4 ops) may remain in flight
    SYNC();

    // ---------- Phase 1: t1[k][r] = sum_d z[tok,d] * a1[e,r,d] (LDS a1) ----
    float p[TW][Rr];
#pragma unroll
    for (int k = 0; k < TW; ++k)
#pragma unroll
        for (int r = 0; r < Rr; ++r) p[k][r] = 0.f;

#pragma unroll
    for (int i = 0; i < Zd / 4 / 64; ++i) {         // 4 iters
        const int c = lane + i * 64;
        float4 zv[TW];
#pragma unroll
        for (int k = 0; k < TW; ++k)
            zv[k] = *(const float4*)(z + (size_t)tok[k] * Zd + 4 * c);
#pragma unroll
        for (int r = 0; r < Rr; ++r) {
            const float4 w = *(const float4*)(s_a1 + r * Zd + 4 * c);
#pragma unroll
            for (int k = 0; k < TW; ++k)
                p[k][r] = fmaf(zv[k].x, w.x, fmaf(zv[k].y, w.y,
                          fmaf(zv[k].z, w.z, fmaf(zv[k].w, w.w, p[k][r]))));
        }
    }
    float t1[TW][Rr];
#pragma unroll
    for (int k = 0; k < TW; ++k)
#pragma unroll
        for (int r = 0; r < Rr; ++r) t1[k][r] = wave_allreduce(p[k][r]);

    SYNC();        // all waves done reading a1; b2 writes land >=900cy later

    // stage b2 into s_a1 region (4 ops, swizzled src) — overlaps phase 2
#pragma unroll
    for (int i = 0; i < 4; ++i) {
        const int o = (i * NT + t) * 16;
        stage16(b2e + swz(o), (char*)s_a1 + (i * NT + wave * 64) * 16);
    }

    // ---------- Phase 2: chunked over H, 3-deep counted-vmcnt pipeline ----
    float q[TW][Rr];
#pragma unroll
    for (int k = 0; k < TW; ++k)
#pragma unroll
        for (int r = 0; r < Rr; ++r) q[k][r] = 0.f;

#pragma unroll
    for (int kc = 0; kc < NCHUNK; ++kc) {
        // wait until own stage(kc) landed (ops issued after it may remain):
        // kc=0: c1(2)+b2(4)=6; kc=1: b2(4)+c2(2)=6; kc=2..6: c(kc+1)=2; kc=7: 0
        if (kc < 2)      { WAITVM(6); }
        else if (kc < 7) { WAITVM(2); }
        else             { WAITVM(0); }
        SYNC();        // all waves' stage(kc) landed; prev chunk reads done

        if (kc + 2 < NCHUNK) {      // issue stage(kc+2) AFTER barrier
            const int nb = (kc + 2) % 3;
            const int hb = (kc + 2) * HC;
            const int o = t * 16;
            stage16(b1e + (size_t)hb * Rr * 4 + swz(o),
                    (char*)s_b1[nb] + wave * 1024);
            stage16(a2e + wave * Hd + hb + lane * 4,
                    (char*)s_a2[nb] + wave * 1024);
        }

        const int cur = kc % 3;
        const int cc = kc * 64 + lane;              // float4 idx into H row
        float4 hv[TW];
#pragma unroll
        for (int k = 0; k < TW; ++k)
            hv[k] = *(const float4*)(h_pre + (size_t)tok[k] * Hd + 4 * cc);

        float sv[TW][4];
#pragma unroll
        for (int j = 0; j < 4; ++j) {
            const int o0 = lane * 128 + j * 32;     // row (4*lane+j) of chunk
            const float4 w0 = *(const float4*)((const char*)s_b1[cur] + swz(o0));
            const float4 w1 = *(const float4*)((const char*)s_b1[cur] + swz(o0 + 16));
#pragma unroll
            for (int k = 0; k < TW; ++k) {
                const float x = (&hv[k].x)[j] + dot8(t1[k], w0, w1) * kScale;
                sv[k][j] = silu(x);
            }
        }
#pragma unroll
        for (int r = 0; r < Rr; ++r) {
            const float4 aw = *(const float4*)(s_a2[cur] + r * HC + lane * 4);
#pragma unroll
            for (int k = 0; k < TW; ++k)
                q[k][r] = fmaf(sv[k][0], aw.x, fmaf(sv[k][1], aw.y,
                          fmaf(sv[k][2], aw.z, fmaf(sv[k][3], aw.w, q[k][r]))));
        }
    }

    float t2[TW][Rr];
#pragma unroll
    for (int k = 0; k < TW; ++k)
#pragma unroll
        for (int r = 0; r < Rr; ++r) t2[k][r] = wave_allreduce(q[k][r]) * kScale;

    // ---------- Phase 3: out = out_pre + t2·b2[e,d,:]  (b2 in s_a1) ----------
    // b2 landed: every wave hit WAITVM(0) before the kc=7 barrier.
#pragma unroll
    for (int i = 0; i < Zd / 4 / 64; ++i) {         // 4 iters
        const int c = lane + i * 64;
        float4 ov[TW];
#pragma unroll
        for (int k = 0; k < TW; ++k)
            ov[k] = *(const float4*)(out_pre + (size_t)tok[k] * Zd + 4 * c);
        float4 res[TW];
#pragma unroll
        for (int j = 0; j < 4; ++j) {
            const int o0 = c * 128 + j * 32;        // row (4c+j), 32 B each
            const float4 w0 = *(const float4*)((const char*)s_a1 + swz(o0));
            const float4 w1 = *(const float4*)((const char*)s_a1 + swz(o0 + 16));
#pragma unroll
            for (int k = 0; k < TW; ++k)
                (&res[k].x)[j] = (&ov[k].x)[j] + dot8(t2[k], w0, w1);
        }
#pragma unroll
        for (int k = 0; k < TW; ++k)
            if (val[k]) *(float4*)(out + (size_t)tok[k] * Zd + 4 * c) = res[k];
    }
}

extern "C" void kernel_launch(void* const* d_in, const int* in_sizes, int n_in,
                              void* d_out, int out_size, void* d_ws, size_t ws_size,
                              hipStream_t stream) {
    const float* z       = (const float*)d_in[0];
    const int*   a_idx   = (const int*)d_in[1];
    const float* h_pre   = (const float*)d_in[2];
    const float* out_pre = (const float*)d_in[3];
    const float* a1      = (const float*)d_in[4];
    const float* b1      = (const float*)d_in[5];
    const float* a2      = (const float*)d_in[6];
    const float* b2      = (const float*)d_in[7];
    float* out = (float*)d_out;

    const int N = in_sizes[1];  // a_idx count

    bucket_kernel<<<1, 1024, 0, stream>>>(a_idx, N, (int*)d_ws);

    int nwg = N / TB + Wn;              // 576 blocks (incl. per-expert tails)
    nwg = (nwg + 7) & ~7;               // multiple of 8 for XCD swizzle
    lora_main<<<nwg, NT, 0, stream>>>(z, h_pre, out_pre, a1, b1, a2, b2, out,
                                      (const int*)d_ws, N);
}